// Round 1
// 452.096 us; speedup vs baseline: 1.3274x; 1.3274x over previous
//
#include <hip/hip_runtime.h>

#define N_NODES 100000
#define N_EDGES 1600000

#define NBK 782    // row buckets of 128 rows: ceil(100000/128)
#define EPB 4096   // edges per binA block
#define NBA 391    // binA blocks: 391*4096 = 1,601,536 >= N_EDGES

typedef __attribute__((ext_vector_type(8))) short short8;
typedef __attribute__((ext_vector_type(4))) float f32x4;

__device__ __forceinline__ ushort f2bf(float f) {
    uint u = __float_as_uint(f);
    return (ushort)((u + 0x7fff + ((u >> 16) & 1)) >> 16);   // RNE
}
__device__ __forceinline__ float bflo(uint p) { return __uint_as_float(p << 16); }
__device__ __forceinline__ float bfhi(uint p) { return __uint_as_float(p & 0xffff0000u); }

// ---------------- CSR build: two-pass counting sort by 128-row bucket ----------------
// Phase A: each block owns a contiguous chunk of EPB edges. LDS histogram over 782
// buckets, LDS scan, then the block writes its edges grouped-by-bucket into its own
// PRIVATE contiguous region of tmp (1x write amplification, L2-combined). Per-
// (bucket,block) offsets/counts go to offT/cntT; bucket totals accumulate in gcount.

__global__ void __launch_bounds__(1024) binA_k(const int* __restrict__ row,
                                               const int* __restrict__ col,
                                               const float* __restrict__ vals,
                                               int2* __restrict__ tmp,
                                               int* __restrict__ gcount,
                                               int* __restrict__ offT,
                                               int* __restrict__ cntT) {
    __shared__ int h[NBK];
    __shared__ int cur[NBK];
    __shared__ int sh[1024];
    int t = threadIdx.x;
    int base = blockIdx.x * EPB;

    if (t < NBK) h[t] = 0;
    __syncthreads();
    for (int i = t; i < EPB; i += 1024) {
        int e = base + i;
        if (e < N_EDGES) atomicAdd(&h[row[e] >> 7], 1);
    }
    __syncthreads();
    if (t < NBK) {
        int c = h[t];
        cntT[t * NBA + blockIdx.x] = c;
        if (c) atomicAdd(&gcount[t], c);
    }
    // exclusive scan of h over 782 (padded to 1024)
    sh[t] = (t < NBK) ? h[t] : 0;
    __syncthreads();
    for (int off = 1; off < 1024; off <<= 1) {
        int v = (t >= off) ? sh[t - off] : 0;
        __syncthreads();
        sh[t] += v;
        __syncthreads();
    }
    if (t < NBK) {
        int ex = t ? sh[t - 1] : 0;
        cur[t] = ex;
        offT[t * NBA + blockIdx.x] = ex;
    }
    __syncthreads();
    // scatter into block-private region, grouped by bucket
    for (int i = t; i < EPB; i += 1024) {
        int e = base + i;
        if (e < N_EDGES) {
            int r = row[e];
            int p = atomicAdd(&cur[r >> 7], 1);
            int2 v;
            v.x = ((r & 127) << 17) | col[e];   // 7-bit row-in-bucket | 17-bit col
            v.y = __float_as_int(vals[e]);
            tmp[base + p] = v;
        }
    }
}

// exclusive scan of the 782 bucket totals -> bstart; also rowptr[N] = E
__global__ void __launch_bounds__(1024) bscan_k(const int* __restrict__ gcount,
                                                int* __restrict__ bstart,
                                                int* __restrict__ rowptr) {
    __shared__ int sh[1024];
    int t = threadIdx.x;
    sh[t] = (t < NBK) ? gcount[t] : 0;
    __syncthreads();
    for (int off = 1; off < 1024; off <<= 1) {
        int v = (t >= off) ? sh[t - off] : 0;
        __syncthreads();
        sh[t] += v;
        __syncthreads();
    }
    if (t < NBK) bstart[t] = t ? sh[t - 1] : 0;
    if (t == 0) rowptr[N_NODES] = N_EDGES;
}

// Phase B: one block per bucket. Gather the bucket's edges from the 391 block
// segments, 128-bin LDS hist+scan (-> rowptr for these 128 rows), then scatter to
// final ep — destinations confined to a contiguous ~16KB window (1x amplification).

__global__ void __launch_bounds__(256) binB_k(const int2* __restrict__ tmp,
                                              const int* __restrict__ offT,
                                              const int* __restrict__ cntT,
                                              const int* __restrict__ bstart,
                                              int* __restrict__ rowptr,
                                              int2* __restrict__ ep) {
    __shared__ int h[128];
    __shared__ int cur[128];
    __shared__ int segoff[NBA];
    __shared__ int segcnt[NBA];
    int b = blockIdx.x, t = threadIdx.x;
    int wv = t >> 6, ln = t & 63;

    for (int i = t; i < NBA; i += 256) {
        segoff[i] = i * EPB + offT[b * NBA + i];
        segcnt[i] = cntT[b * NBA + i];
    }
    if (t < 128) h[t] = 0;
    __syncthreads();
    // pass 1: row-in-bucket histogram
    for (int s = wv; s < NBA; s += 4) {
        int n = segcnt[s], o = segoff[s];
        for (int i = ln; i < n; i += 64) atomicAdd(&h[tmp[o + i].x >> 17], 1);
    }
    __syncthreads();
    // exclusive scan over 128 bins
    for (int off = 1; off < 128; off <<= 1) {
        int v = (t >= off && t < 128) ? h[t - off] : 0;
        __syncthreads();
        if (t < 128) h[t] += v;
        __syncthreads();
    }
    int bs = bstart[b];
    if (t < 128) {
        int ex = t ? h[t - 1] : 0;
        cur[t] = ex;
        int r = (b << 7) + t;
        if (r < N_NODES) rowptr[r] = bs + ex;
    }
    __syncthreads();
    // pass 2: scatter to final CSR positions (tmp segments are L2-hot from pass 1)
    for (int s = wv; s < NBA; s += 4) {
        int n = segcnt[s], o = segoff[s];
        for (int i = ln; i < n; i += 64) {
            int2 v = tmp[o + i];
            int p = atomicAdd(&cur[v.x >> 17], 1);
            int2 w;
            w.x = v.x & 0x1ffff;
            w.y = v.y;
            ep[bs + p] = w;
        }
    }
}

// ---------------- converts ----------------

__global__ void cvtx_k(const float* __restrict__ x, ushort* __restrict__ xb, int n4) {
    int i = blockIdx.x * 256 + threadIdx.x;
    if (i < n4) {
        float4 v = ((const float4*)x)[i];
        uint2 o;
        o.x = (uint)f2bf(v.x) | ((uint)f2bf(v.y) << 16);
        o.y = (uint)f2bf(v.z) | ((uint)f2bf(v.w) << 16);
        ((uint2*)xb)[i] = o;
    }
}

// transpose-convert all three weight matrices: Wt[n][k] = bf16(W[k][n])
__global__ void wcvt_k(const float* __restrict__ W1, const float* __restrict__ W2,
                       const float* __restrict__ W3, ushort* __restrict__ Wt1,
                       ushort* __restrict__ Wt2, ushort* __restrict__ Wt3) {
    int i = blockIdx.x * 256 + threadIdx.x;
    if (i < 16384) {
        int n = i >> 7, k = i & 127;
        Wt1[i] = f2bf(W1[k * 128 + n]);
        Wt2[i] = f2bf(W2[k * 128 + n]);
    }
    if (i < 8192) {
        int n = i >> 7, k = i & 127;
        Wt3[i] = f2bf(W3[k * 64 + n]);
    }
}

// ---------------- GEMM: Y[r, 0..DN) = bf16( Xb[r,:] @ Wt^T + bias ) ----------------
// MFMA 16x16x32 bf16. A: lane l elem j -> A[l&15][8*(l>>4)+j] (row-major Xb [M][128])
// B: lane l elem j -> B[8*(l>>4)+j][l&15]  (Wt stored [N][K] row-major)
// D: lane l reg i  -> D[4*(l>>4)+i][l&15]

template <int DN>
__global__ void __launch_bounds__(256) gemm_k(const ushort* __restrict__ Xb,
                                              const ushort* __restrict__ Wt,
                                              const float* __restrict__ bias,
                                              ushort* __restrict__ Y) {
    constexpr int NT = DN / 16;
    int wv = threadIdx.x >> 6;
    int l = threadIdx.x & 63;
    int lg = l >> 4, lm = l & 15;
    int rbase = blockIdx.x * 64 + wv * 16;

    int arow = rbase + lm;
    if (arow > N_NODES - 1) arow = N_NODES - 1;     // clamp (stores predicated)
    const short8* aptr = (const short8*)(Xb + (size_t)arow * 128 + lg * 8);

    f32x4 acc[NT];
#pragma unroll
    for (int n = 0; n < NT; n++) acc[n] = (f32x4){0.f, 0.f, 0.f, 0.f};

#pragma unroll
    for (int kk = 0; kk < 4; ++kk) {
        short8 a = aptr[kk * 4];                    // 32 elems = 4 short8 per k-step
#pragma unroll
        for (int n = 0; n < NT; ++n) {
            short8 b = *(const short8*)(Wt + (size_t)(n * 16 + lm) * 128 + kk * 32 + lg * 8);
            acc[n] = __builtin_amdgcn_mfma_f32_16x16x32_bf16(a, b, acc[n], 0, 0, 0);
        }
    }

    int r0 = rbase + lg * 4;
#pragma unroll
    for (int n = 0; n < NT; ++n) {
        int c = n * 16 + lm;
        float bj = bias[c];
#pragma unroll
        for (int i = 0; i < 4; ++i) {
            int r = r0 + i;
            if (r < N_NODES) Y[(size_t)r * DN + c] = f2bf(acc[n][i] + bj);
        }
    }
}

// ---------------- SpMM (CSR, one wave per row, bf16 gather, fp32 accum) ----------------

template <int D, bool RELU, bool OUT_BF16>
__global__ void __launch_bounds__(256) spmm_k(const int* __restrict__ rowptr,
                                              const int2* __restrict__ ep,
                                              const ushort* __restrict__ xb,
                                              void* __restrict__ y) {
    int w = blockIdx.x * 4 + (threadIdx.x >> 6);
    int lane = threadIdx.x & 63;
    if (w >= N_NODES) return;
    int s = rowptr[w], e = rowptr[w + 1];

    if (D == 128) {
        const uint* xp = (const uint*)xb + lane;    // pairs; row stride 64 uints
        float a0 = 0.f, a1 = 0.f;
        int i = s;
        for (; i + 3 < e; i += 4) {
            int2 e0 = ep[i], e1 = ep[i + 1], e2 = ep[i + 2], e3 = ep[i + 3];
            uint x0 = xp[(size_t)e0.x * 64];
            uint x1 = xp[(size_t)e1.x * 64];
            uint x2 = xp[(size_t)e2.x * 64];
            uint x3 = xp[(size_t)e3.x * 64];
            float v0 = __int_as_float(e0.y), v1 = __int_as_float(e1.y);
            float v2 = __int_as_float(e2.y), v3 = __int_as_float(e3.y);
            a0 = fmaf(v0, bflo(x0), a0); a1 = fmaf(v0, bfhi(x0), a1);
            a0 = fmaf(v1, bflo(x1), a0); a1 = fmaf(v1, bfhi(x1), a1);
            a0 = fmaf(v2, bflo(x2), a0); a1 = fmaf(v2, bfhi(x2), a1);
            a0 = fmaf(v3, bflo(x3), a0); a1 = fmaf(v3, bfhi(x3), a1);
        }
        for (; i < e; ++i) {
            int2 e0 = ep[i];
            uint x0 = xp[(size_t)e0.x * 64];
            float v0 = __int_as_float(e0.y);
            a0 = fmaf(v0, bflo(x0), a0); a1 = fmaf(v0, bfhi(x0), a1);
        }
        if (RELU) { a0 = fmaxf(a0, 0.f); a1 = fmaxf(a1, 0.f); }
        ((uint*)y)[(size_t)w * 64 + lane] = (uint)f2bf(a0) | ((uint)f2bf(a1) << 16);
    } else {  // D == 64
        const ushort* xp = xb + lane;
        float a0 = 0.f;
        int i = s;
        for (; i + 3 < e; i += 4) {
            int2 e0 = ep[i], e1 = ep[i + 1], e2 = ep[i + 2], e3 = ep[i + 3];
            float x0 = __uint_as_float((uint)xp[(size_t)e0.x * 64] << 16);
            float x1 = __uint_as_float((uint)xp[(size_t)e1.x * 64] << 16);
            float x2 = __uint_as_float((uint)xp[(size_t)e2.x * 64] << 16);
            float x3 = __uint_as_float((uint)xp[(size_t)e3.x * 64] << 16);
            a0 = fmaf(__int_as_float(e0.y), x0, a0);
            a0 = fmaf(__int_as_float(e1.y), x1, a0);
            a0 = fmaf(__int_as_float(e2.y), x2, a0);
            a0 = fmaf(__int_as_float(e3.y), x3, a0);
        }
        for (; i < e; ++i) {
            int2 e0 = ep[i];
            float x0 = __uint_as_float((uint)xp[(size_t)e0.x * 64] << 16);
            a0 = fmaf(__int_as_float(e0.y), x0, a0);
        }
        if (RELU) a0 = fmaxf(a0, 0.f);
        ((float*)y)[(size_t)w * 64 + lane] = a0;   // final output fp32
    }
}

// ---------------- launch ----------------

extern "C" void kernel_launch(void* const* d_in, const int* in_sizes, int n_in,
                              void* d_out, int out_size, void* d_ws, size_t ws_size,
                              hipStream_t stream) {
    const float* x    = (const float*)d_in[0];
    const float* vals = (const float*)d_in[1];
    const float* W1   = (const float*)d_in[2];
    const float* b1   = (const float*)d_in[3];
    const float* W2   = (const float*)d_in[4];
    const float* b2   = (const float*)d_in[5];
    const float* W3   = (const float*)d_in[6];
    const float* b3   = (const float*)d_in[7];
    const int* row    = (const int*)d_in[8];
    const int* col    = (const int*)d_in[9];
    float* out = (float*)d_out;

    char* ws = (char*)d_ws;
    int2*   ep     = (int2*)  (ws + 0);          // 12,800,000
    int*    rowptr = (int*)   (ws + 12800000);   // 400,004
    ushort* Wt1    = (ushort*)(ws + 13601024);   // 32,768
    ushort* Wt2    = (ushort*)(ws + 13633792);   // 32,768
    ushort* Wt3    = (ushort*)(ws + 13666560);   // 16,384
    ushort* xb0    = (ushort*)(ws + 16000000);   // 25,600,000 (reused as g64)
    ushort* g      = (ushort*)(ws + 41600000);   // 25,600,000
    ushort* sbuf   = (ushort*)(ws + 67200000);   // 25,600,000  (total 92.8MB)
    ushort* g64    = xb0;                        // layer-3 gemm out, xb0 dead by then

    // build-time aliases: tmp lives in g (dead until gemm L1); tables live in sbuf
    // (dead until spmm L1). All build kernels complete before those are written.
    int2* tmp    = (int2*)g;                     // NBA*EPB*8 = 12,812,288 <= 25.6MB
    int*  gcount = (int*)sbuf;                   // 3,128
    int*  bstart = (int*)(ws + 67200000 + 4096); // 3,128
    int*  offT   = (int*)(ws + 67200000 + 8192);            // 782*391*4 = 1,223,048
    int*  cntT   = (int*)(ws + 67200000 + 8192 + 1232896);  // 1,223,048 (ends ~2.46MB)

    // CSR build (counting sort by 128-row bucket)
    hipMemsetAsync(gcount, 0, NBK * sizeof(int), stream);
    hipLaunchKernelGGL(binA_k, dim3(NBA), dim3(1024), 0, stream,
                       row, col, vals, tmp, gcount, offT, cntT);
    hipLaunchKernelGGL(bscan_k, dim3(1), dim3(1024), 0, stream, gcount, bstart, rowptr);
    hipLaunchKernelGGL(binB_k, dim3(NBK), dim3(256), 0, stream,
                       tmp, offT, cntT, bstart, rowptr, ep);

    // converts
    hipLaunchKernelGGL(cvtx_k, dim3((N_NODES * 128 / 4 + 255) / 256), dim3(256), 0, stream,
                       x, xb0, N_NODES * 128 / 4);
    hipLaunchKernelGGL(wcvt_k, dim3(64), dim3(256), 0, stream, W1, W2, W3, Wt1, Wt2, Wt3);

    const int GEMM_GRID = (N_NODES + 63) / 64;   // 1563
    const int SPMM_GRID = (N_NODES + 3) / 4;     // 25000

    // layer 1
    hipLaunchKernelGGL((gemm_k<128>), dim3(GEMM_GRID), dim3(256), 0, stream, xb0, Wt1, b1, g);
    hipLaunchKernelGGL((spmm_k<128, true, true>), dim3(SPMM_GRID), dim3(256), 0, stream,
                       rowptr, ep, g, sbuf);
    // layer 2
    hipLaunchKernelGGL((gemm_k<128>), dim3(GEMM_GRID), dim3(256), 0, stream, sbuf, Wt2, b2, g);
    hipLaunchKernelGGL((spmm_k<128, true, true>), dim3(SPMM_GRID), dim3(256), 0, stream,
                       rowptr, ep, g, sbuf);
    // layer 3
    hipLaunchKernelGGL((gemm_k<64>), dim3(GEMM_GRID), dim3(256), 0, stream, sbuf, Wt3, b3, g64);
    hipLaunchKernelGGL((spmm_k<64, false, false>), dim3(SPMM_GRID), dim3(256), 0, stream,
                       rowptr, ep, g64, out);
}

// Round 2
// 364.909 us; speedup vs baseline: 1.6446x; 1.2389x over previous
//
#include <hip/hip_runtime.h>

#define N_NODES 100000
#define N_EDGES 1600000

#define NBK 782    // row buckets of 128 rows: ceil(100000/128)
#define EPB 8192   // edges per binA block
#define NBA 196    // binA blocks: 196*8192 = 1,605,632 >= N_EDGES
#define CAPE 4096  // LDS edge-stage capacity in binB (mean bucket = 2046)

typedef __attribute__((ext_vector_type(8))) short short8;
typedef __attribute__((ext_vector_type(4))) float f32x4;

__device__ __forceinline__ ushort f2bf(float f) {
    uint u = __float_as_uint(f);
    return (ushort)((u + 0x7fff + ((u >> 16) & 1)) >> 16);   // RNE
}
__device__ __forceinline__ float bflo(uint p) { return __uint_as_float(p << 16); }
__device__ __forceinline__ float bfhi(uint p) { return __uint_as_float(p & 0xffff0000u); }

// ---------------- CSR build: two-pass counting sort by 128-row bucket ----------------
// Phase A: each block owns EPB contiguous edges, stages them in registers, builds an
// LDS histogram over 782 buckets, scans it, and writes its edges grouped-by-bucket
// into its PRIVATE contiguous region of tmp (1x write amplification). Only the
// per-(bucket,block) exclusive offsets go to offT; counts are offT row differences.

__global__ void __launch_bounds__(1024) binA_k(const int* __restrict__ row,
                                               const int* __restrict__ col,
                                               const float* __restrict__ vals,
                                               int2* __restrict__ tmp,
                                               int* __restrict__ gcount,
                                               int* __restrict__ offT) {
    __shared__ int h[NBK];
    __shared__ int cur[NBK];
    __shared__ int sh[1024];
    int t = threadIdx.x;
    int base = blockIdx.x * EPB;

    // stage 8 edges/thread in registers (row/col/vals each read exactly once)
    int rr[8], cc[8];
    float vv[8];
#pragma unroll
    for (int u = 0; u < 8; ++u) {
        int e = base + u * 1024 + t;
        bool ok = (e < N_EDGES);
        rr[u] = ok ? row[e] : -1;
        cc[u] = ok ? col[e] : 0;
        vv[u] = ok ? vals[e] : 0.f;
    }

    if (t < NBK) h[t] = 0;
    __syncthreads();
#pragma unroll
    for (int u = 0; u < 8; ++u)
        if (rr[u] >= 0) atomicAdd(&h[rr[u] >> 7], 1);
    __syncthreads();
    if (t < NBK && h[t]) atomicAdd(&gcount[t], h[t]);
    // exclusive scan of h over NBK (padded to 1024)
    sh[t] = (t < NBK) ? h[t] : 0;
    __syncthreads();
    for (int off = 1; off < 1024; off <<= 1) {
        int v = (t >= off) ? sh[t - off] : 0;
        __syncthreads();
        sh[t] += v;
        __syncthreads();
    }
    if (t < NBK) {
        int ex = t ? sh[t - 1] : 0;
        cur[t] = ex;
        offT[t * NBA + blockIdx.x] = ex;
    }
    if (t == NBK - 1) offT[NBK * NBA + blockIdx.x] = sh[t];  // row NBK = edges in block
    __syncthreads();
    // scatter into block-private region, grouped by bucket
#pragma unroll
    for (int u = 0; u < 8; ++u) {
        if (rr[u] >= 0) {
            int p = atomicAdd(&cur[rr[u] >> 7], 1);
            int2 v;
            v.x = ((rr[u] & 127) << 17) | cc[u];   // 7-bit row-in-bucket | 17-bit col
            v.y = __float_as_int(vv[u]);
            tmp[base + p] = v;
        }
    }
}

// exclusive scan of the 782 bucket totals -> bstart; also rowptr[N] = E
__global__ void __launch_bounds__(1024) bscan_k(const int* __restrict__ gcount,
                                                int* __restrict__ bstart,
                                                int* __restrict__ rowptr) {
    __shared__ int sh[1024];
    int t = threadIdx.x;
    sh[t] = (t < NBK) ? gcount[t] : 0;
    __syncthreads();
    for (int off = 1; off < 1024; off <<= 1) {
        int v = (t >= off) ? sh[t - off] : 0;
        __syncthreads();
        sh[t] += v;
        __syncthreads();
    }
    if (t < NBK) bstart[t] = t ? sh[t - 1] : 0;
    if (t == 0) rowptr[N_NODES] = N_EDGES;
}

// Phase B: one block per bucket. Flat-index over the bucket's edges: each lane
// binary-searches its segment (LDS, 8 steps), reads tmp ONCE (coalesced), histograms
// and stages the edge in LDS; after a 128-bin scan (-> rowptr), the scatter pass runs
// from LDS into a contiguous ~16KB window of ep (1x write amplification).

__global__ void __launch_bounds__(256) binB_k(const int2* __restrict__ tmp,
                                              const int* __restrict__ offT,
                                              const int* __restrict__ bstart,
                                              int* __restrict__ rowptr,
                                              int2* __restrict__ ep) {
    __shared__ int goff[NBA];
    __shared__ int sstart[NBA];
    __shared__ int s_scan[256];
    __shared__ int h[128];
    __shared__ int cur[128];
    __shared__ int2 ebuf[CAPE];
    __shared__ int sT;
    int b = blockIdx.x, t = threadIdx.x;

    int c = 0;
    if (t < NBA) {
        int o0 = offT[b * NBA + t];
        int o1 = offT[(b + 1) * NBA + t];
        c = o1 - o0;
        goff[t] = t * EPB + o0;
    }
    s_scan[t] = c;
    __syncthreads();
    for (int off = 1; off < 256; off <<= 1) {
        int v = (t >= off) ? s_scan[t - off] : 0;
        __syncthreads();
        s_scan[t] += v;
        __syncthreads();
    }
    if (t < NBA) sstart[t] = s_scan[t] - c;
    if (t == NBA - 1) sT = s_scan[t];
    if (t < 128) h[t] = 0;
    __syncthreads();
    int T = sT;

    // load + histogram + stage
    for (int j = t; j < T; j += 256) {
        int lo = 0, hi = NBA - 1;            // last s with sstart[s] <= j
        while (lo < hi) {
            int mid = (lo + hi + 1) >> 1;
            if (sstart[mid] <= j) lo = mid; else hi = mid - 1;
        }
        int2 v = tmp[goff[lo] + (j - sstart[lo])];
        atomicAdd(&h[v.x >> 17], 1);
        if (j < CAPE) ebuf[j] = v;
    }
    __syncthreads();
    // exclusive scan over 128 bins
    for (int off = 1; off < 128; off <<= 1) {
        int v = (t >= off && t < 128) ? h[t - off] : 0;
        __syncthreads();
        if (t < 128) h[t] += v;
        __syncthreads();
    }
    int bs = bstart[b];
    if (t < 128) {
        int ex = t ? h[t - 1] : 0;
        cur[t] = ex;
        int r = (b << 7) + t;
        if (r < N_NODES) rowptr[r] = bs + ex;
    }
    __syncthreads();
    // scatter to final CSR positions (from LDS; overflow re-reads global)
    for (int j = t; j < T; j += 256) {
        int2 v;
        if (j < CAPE) v = ebuf[j];
        else {
            int lo = 0, hi = NBA - 1;
            while (lo < hi) {
                int mid = (lo + hi + 1) >> 1;
                if (sstart[mid] <= j) lo = mid; else hi = mid - 1;
            }
            v = tmp[goff[lo] + (j - sstart[lo])];
        }
        int p = atomicAdd(&cur[v.x >> 17], 1);
        int2 w;
        w.x = v.x & 0x1ffff;
        w.y = v.y;
        ep[bs + p] = w;
    }
}

// ---------------- converts ----------------

// transpose-convert all three weight matrices: Wt[n][k] = bf16(W[k][n])
__global__ void wcvt_k(const float* __restrict__ W1, const float* __restrict__ W2,
                       const float* __restrict__ W3, ushort* __restrict__ Wt1,
                       ushort* __restrict__ Wt2, ushort* __restrict__ Wt3) {
    int i = blockIdx.x * 256 + threadIdx.x;
    if (i < 16384) {
        int n = i >> 7, k = i & 127;
        Wt1[i] = f2bf(W1[k * 128 + n]);
        Wt2[i] = f2bf(W2[k * 128 + n]);
    }
    if (i < 8192) {
        int n = i >> 7, k = i & 127;
        Wt3[i] = f2bf(W3[k * 64 + n]);
    }
}

// ---------------- GEMM: Y[r, 0..DN) = bf16( X[r,:] @ Wt^T + bias ) ----------------
// MFMA 16x16x32 bf16. A: lane l elem j -> A[l&15][8*(l>>4)+j] (row-major X [M][128])
// B: lane l elem j -> B[8*(l>>4)+j][l&15]  (Wt stored [N][K] row-major)
// D: lane l reg i  -> D[4*(l>>4)+i][l&15]
// AF32: A is fp32 and converted in-register (fuses the old cvtx pass into layer 1).

template <int DN, bool AF32>
__global__ void __launch_bounds__(256) gemm_k(const void* __restrict__ Xa,
                                              const ushort* __restrict__ Wt,
                                              const float* __restrict__ bias,
                                              ushort* __restrict__ Y) {
    constexpr int NT = DN / 16;
    const ushort* Xb = (const ushort*)Xa;
    const float* Xf = (const float*)Xa;
    int wv = threadIdx.x >> 6;
    int l = threadIdx.x & 63;
    int lg = l >> 4, lm = l & 15;
    int rbase = blockIdx.x * 64 + wv * 16;

    int arow = rbase + lm;
    if (arow > N_NODES - 1) arow = N_NODES - 1;     // clamp (stores predicated)

    f32x4 acc[NT];
#pragma unroll
    for (int n = 0; n < NT; n++) acc[n] = (f32x4){0.f, 0.f, 0.f, 0.f};

#pragma unroll
    for (int kk = 0; kk < 4; ++kk) {
        short8 a;
        if constexpr (AF32) {
            const float* ap = Xf + (size_t)arow * 128 + kk * 32 + lg * 8;
            float4 u = *(const float4*)ap;
            float4 v = *(const float4*)(ap + 4);
            a = (short8){(short)f2bf(u.x), (short)f2bf(u.y), (short)f2bf(u.z), (short)f2bf(u.w),
                         (short)f2bf(v.x), (short)f2bf(v.y), (short)f2bf(v.z), (short)f2bf(v.w)};
        } else {
            a = *(const short8*)(Xb + (size_t)arow * 128 + kk * 32 + lg * 8);
        }
#pragma unroll
        for (int n = 0; n < NT; ++n) {
            short8 b = *(const short8*)(Wt + (size_t)(n * 16 + lm) * 128 + kk * 32 + lg * 8);
            acc[n] = __builtin_amdgcn_mfma_f32_16x16x32_bf16(a, b, acc[n], 0, 0, 0);
        }
    }

    int r0 = rbase + lg * 4;
#pragma unroll
    for (int n = 0; n < NT; ++n) {
        int c = n * 16 + lm;
        float bj = bias[c];
#pragma unroll
        for (int i = 0; i < 4; ++i) {
            int r = r0 + i;
            if (r < N_NODES) Y[(size_t)r * DN + c] = f2bf(acc[n][i] + bj);
        }
    }
}

// ---------------- SpMM (CSR, one wave per row, bf16 gather, fp32 accum) ----------------

template <int D, bool RELU, bool OUT_BF16>
__global__ void __launch_bounds__(256) spmm_k(const int* __restrict__ rowptr,
                                              const int2* __restrict__ ep,
                                              const ushort* __restrict__ xb,
                                              void* __restrict__ y) {
    int w = blockIdx.x * 4 + (threadIdx.x >> 6);
    int lane = threadIdx.x & 63;
    if (w >= N_NODES) return;
    int s = rowptr[w], e = rowptr[w + 1];

    if (D == 128) {
        const uint* xp = (const uint*)xb + lane;    // pairs; row stride 64 uints
        float a0 = 0.f, a1 = 0.f;
        int i = s;
        for (; i + 3 < e; i += 4) {
            int2 e0 = ep[i], e1 = ep[i + 1], e2 = ep[i + 2], e3 = ep[i + 3];
            uint x0 = xp[(size_t)e0.x * 64];
            uint x1 = xp[(size_t)e1.x * 64];
            uint x2 = xp[(size_t)e2.x * 64];
            uint x3 = xp[(size_t)e3.x * 64];
            float v0 = __int_as_float(e0.y), v1 = __int_as_float(e1.y);
            float v2 = __int_as_float(e2.y), v3 = __int_as_float(e3.y);
            a0 = fmaf(v0, bflo(x0), a0); a1 = fmaf(v0, bfhi(x0), a1);
            a0 = fmaf(v1, bflo(x1), a0); a1 = fmaf(v1, bfhi(x1), a1);
            a0 = fmaf(v2, bflo(x2), a0); a1 = fmaf(v2, bfhi(x2), a1);
            a0 = fmaf(v3, bflo(x3), a0); a1 = fmaf(v3, bfhi(x3), a1);
        }
        for (; i < e; ++i) {
            int2 e0 = ep[i];
            uint x0 = xp[(size_t)e0.x * 64];
            float v0 = __int_as_float(e0.y);
            a0 = fmaf(v0, bflo(x0), a0); a1 = fmaf(v0, bfhi(x0), a1);
        }
        if (RELU) { a0 = fmaxf(a0, 0.f); a1 = fmaxf(a1, 0.f); }
        ((uint*)y)[(size_t)w * 64 + lane] = (uint)f2bf(a0) | ((uint)f2bf(a1) << 16);
    } else {  // D == 64
        const ushort* xp = xb + lane;
        float a0 = 0.f;
        int i = s;
        for (; i + 3 < e; i += 4) {
            int2 e0 = ep[i], e1 = ep[i + 1], e2 = ep[i + 2], e3 = ep[i + 3];
            float x0 = __uint_as_float((uint)xp[(size_t)e0.x * 64] << 16);
            float x1 = __uint_as_float((uint)xp[(size_t)e1.x * 64] << 16);
            float x2 = __uint_as_float((uint)xp[(size_t)e2.x * 64] << 16);
            float x3 = __uint_as_float((uint)xp[(size_t)e3.x * 64] << 16);
            a0 = fmaf(__int_as_float(e0.y), x0, a0);
            a0 = fmaf(__int_as_float(e1.y), x1, a0);
            a0 = fmaf(__int_as_float(e2.y), x2, a0);
            a0 = fmaf(__int_as_float(e3.y), x3, a0);
        }
        for (; i < e; ++i) {
            int2 e0 = ep[i];
            float x0 = __uint_as_float((uint)xp[(size_t)e0.x * 64] << 16);
            a0 = fmaf(__int_as_float(e0.y), x0, a0);
        }
        if (RELU) a0 = fmaxf(a0, 0.f);
        ((float*)y)[(size_t)w * 64 + lane] = a0;   // final output fp32
    }
}

// ---------------- launch ----------------

extern "C" void kernel_launch(void* const* d_in, const int* in_sizes, int n_in,
                              void* d_out, int out_size, void* d_ws, size_t ws_size,
                              hipStream_t stream) {
    const float* x    = (const float*)d_in[0];
    const float* vals = (const float*)d_in[1];
    const float* W1   = (const float*)d_in[2];
    const float* b1   = (const float*)d_in[3];
    const float* W2   = (const float*)d_in[4];
    const float* b2   = (const float*)d_in[5];
    const float* W3   = (const float*)d_in[6];
    const float* b3   = (const float*)d_in[7];
    const int* row    = (const int*)d_in[8];
    const int* col    = (const int*)d_in[9];
    float* out = (float*)d_out;

    char* ws = (char*)d_ws;
    int2*   ep     = (int2*)  (ws + 0);          // 12,800,000
    int*    rowptr = (int*)   (ws + 12800000);   // 400,004
    ushort* Wt1    = (ushort*)(ws + 13601024);   // 32,768
    ushort* Wt2    = (ushort*)(ws + 13633792);   // 32,768
    ushort* Wt3    = (ushort*)(ws + 13666560);   // 16,384
    ushort* g64    = (ushort*)(ws + 16000000);   // 12,800,000 (layer-3 gemm out)
    ushort* g      = (ushort*)(ws + 41600000);   // 25,600,000
    ushort* sbuf   = (ushort*)(ws + 67200000);   // 25,600,000  (total 92.8MB)

    // build-time aliases: tmp lives in g (dead until gemm L1); tables live in sbuf
    // (dead until spmm L1 writes it). All build kernels complete before then.
    int2* tmp    = (int2*)g;                     // NBA*EPB*8 = 12,845,056 <= 25.6MB
    int*  gcount = (int*)sbuf;                   // 3,128
    int*  bstart = (int*)(ws + 67200000 + 4096); // 3,128
    int*  offT   = (int*)(ws + 67200000 + 8192); // (NBK+1)*NBA*4 = 613,872

    // CSR build (counting sort by 128-row bucket)
    hipMemsetAsync(gcount, 0, NBK * sizeof(int), stream);
    hipLaunchKernelGGL(binA_k, dim3(NBA), dim3(1024), 0, stream,
                       row, col, vals, tmp, gcount, offT);
    hipLaunchKernelGGL(bscan_k, dim3(1), dim3(1024), 0, stream, gcount, bstart, rowptr);
    hipLaunchKernelGGL(binB_k, dim3(NBK), dim3(256), 0, stream,
                       tmp, offT, bstart, rowptr, ep);

    // weight converts
    hipLaunchKernelGGL(wcvt_k, dim3(64), dim3(256), 0, stream, W1, W2, W3, Wt1, Wt2, Wt3);

    const int GEMM_GRID = (N_NODES + 63) / 64;   // 1563
    const int SPMM_GRID = (N_NODES + 3) / 4;     // 25000

    // layer 1 (gemm reads fp32 x directly, converts in-register)
    hipLaunchKernelGGL((gemm_k<128, true>), dim3(GEMM_GRID), dim3(256), 0, stream, x, Wt1, b1, g);
    hipLaunchKernelGGL((spmm_k<128, true, true>), dim3(SPMM_GRID), dim3(256), 0, stream,
                       rowptr, ep, g, sbuf);
    // layer 2
    hipLaunchKernelGGL((gemm_k<128, false>), dim3(GEMM_GRID), dim3(256), 0, stream, sbuf, Wt2, b2, g);
    hipLaunchKernelGGL((spmm_k<128, true, true>), dim3(SPMM_GRID), dim3(256), 0, stream,
                       rowptr, ep, g, sbuf);
    // layer 3
    hipLaunchKernelGGL((gemm_k<64, false>), dim3(GEMM_GRID), dim3(256), 0, stream, sbuf, Wt3, b3, g64);
    hipLaunchKernelGGL((spmm_k<64, false, false>), dim3(SPMM_GRID), dim3(256), 0, stream,
                       rowptr, ep, g64, out);
}

// Round 3
// 348.657 us; speedup vs baseline: 1.7213x; 1.0466x over previous
//
#include <hip/hip_runtime.h>

#define N_NODES 100000
#define N_EDGES 1600000

#define NBK 782    // row buckets of 128 rows: ceil(100000/128)
#define EPB 8192   // edges per binA block
#define NBA 196    // binA blocks: 196*8192 = 1,605,632 >= N_EDGES
#define CAPE 4096  // LDS edge-stage capacity in binB (mean bucket = 2046)

typedef __attribute__((ext_vector_type(8))) short short8;
typedef __attribute__((ext_vector_type(4))) float f32x4;

__device__ __forceinline__ ushort f2bf(float f) {
    uint u = __float_as_uint(f);
    return (ushort)((u + 0x7fff + ((u >> 16) & 1)) >> 16);   // RNE
}
__device__ __forceinline__ float bflo(uint p) { return __uint_as_float(p << 16); }
__device__ __forceinline__ float bfhi(uint p) { return __uint_as_float(p & 0xffff0000u); }

// ---------------- CSR build: two-pass counting sort by 128-row bucket ----------------

__global__ void __launch_bounds__(1024) binA_k(const int* __restrict__ row,
                                               const int* __restrict__ col,
                                               const float* __restrict__ vals,
                                               int2* __restrict__ tmp,
                                               int* __restrict__ gcount,
                                               int* __restrict__ offT) {
    __shared__ int h[NBK];
    __shared__ int cur[NBK];
    __shared__ int sh[1024];
    int t = threadIdx.x;
    int base = blockIdx.x * EPB;

    // stage 8 edges/thread in registers (row/col/vals each read exactly once)
    int rr[8], cc[8];
    float vv[8];
#pragma unroll
    for (int u = 0; u < 8; ++u) {
        int e = base + u * 1024 + t;
        bool ok = (e < N_EDGES);
        rr[u] = ok ? row[e] : -1;
        cc[u] = ok ? col[e] : 0;
        vv[u] = ok ? vals[e] : 0.f;
    }

    if (t < NBK) h[t] = 0;
    __syncthreads();
#pragma unroll
    for (int u = 0; u < 8; ++u)
        if (rr[u] >= 0) atomicAdd(&h[rr[u] >> 7], 1);
    __syncthreads();
    if (t < NBK && h[t]) atomicAdd(&gcount[t], h[t]);
    // exclusive scan of h over NBK (padded to 1024)
    sh[t] = (t < NBK) ? h[t] : 0;
    __syncthreads();
    for (int off = 1; off < 1024; off <<= 1) {
        int v = (t >= off) ? sh[t - off] : 0;
        __syncthreads();
        sh[t] += v;
        __syncthreads();
    }
    if (t < NBK) {
        int ex = t ? sh[t - 1] : 0;
        cur[t] = ex;
        offT[t * NBA + blockIdx.x] = ex;
    }
    if (t == NBK - 1) offT[NBK * NBA + blockIdx.x] = sh[t];  // row NBK = edges in block
    __syncthreads();
    // scatter into block-private region, grouped by bucket
#pragma unroll
    for (int u = 0; u < 8; ++u) {
        if (rr[u] >= 0) {
            int p = atomicAdd(&cur[rr[u] >> 7], 1);
            int2 v;
            v.x = ((rr[u] & 127) << 17) | cc[u];   // 7-bit row-in-bucket | 17-bit col
            v.y = __float_as_int(vv[u]);
            tmp[base + p] = v;
        }
    }
}

// exclusive scan of the 782 bucket totals -> bstart; also rowptr[N] = E
__global__ void __launch_bounds__(1024) bscan_k(const int* __restrict__ gcount,
                                                int* __restrict__ bstart,
                                                int* __restrict__ rowptr) {
    __shared__ int sh[1024];
    int t = threadIdx.x;
    sh[t] = (t < NBK) ? gcount[t] : 0;
    __syncthreads();
    for (int off = 1; off < 1024; off <<= 1) {
        int v = (t >= off) ? sh[t - off] : 0;
        __syncthreads();
        sh[t] += v;
        __syncthreads();
    }
    if (t < NBK) bstart[t] = t ? sh[t - 1] : 0;
    if (t == 0) rowptr[N_NODES] = N_EDGES;
}

// Phase B: one block per bucket; flat-index gather, LDS stage, scatter from LDS.

__global__ void __launch_bounds__(256) binB_k(const int2* __restrict__ tmp,
                                              const int* __restrict__ offT,
                                              const int* __restrict__ bstart,
                                              int* __restrict__ rowptr,
                                              int2* __restrict__ ep) {
    __shared__ int goff[NBA];
    __shared__ int sstart[NBA];
    __shared__ int s_scan[256];
    __shared__ int h[128];
    __shared__ int cur[128];
    __shared__ int2 ebuf[CAPE];
    __shared__ int sT;
    int b = blockIdx.x, t = threadIdx.x;

    int c = 0;
    if (t < NBA) {
        int o0 = offT[b * NBA + t];
        int o1 = offT[(b + 1) * NBA + t];
        c = o1 - o0;
        goff[t] = t * EPB + o0;
    }
    s_scan[t] = c;
    __syncthreads();
    for (int off = 1; off < 256; off <<= 1) {
        int v = (t >= off) ? s_scan[t - off] : 0;
        __syncthreads();
        s_scan[t] += v;
        __syncthreads();
    }
    if (t < NBA) sstart[t] = s_scan[t] - c;
    if (t == NBA - 1) sT = s_scan[t];
    if (t < 128) h[t] = 0;
    __syncthreads();
    int T = sT;

    // load + histogram + stage
    for (int j = t; j < T; j += 256) {
        int lo = 0, hi = NBA - 1;            // last s with sstart[s] <= j
        while (lo < hi) {
            int mid = (lo + hi + 1) >> 1;
            if (sstart[mid] <= j) lo = mid; else hi = mid - 1;
        }
        int2 v = tmp[goff[lo] + (j - sstart[lo])];
        atomicAdd(&h[v.x >> 17], 1);
        if (j < CAPE) ebuf[j] = v;
    }
    __syncthreads();
    // exclusive scan over 128 bins
    for (int off = 1; off < 128; off <<= 1) {
        int v = (t >= off && t < 128) ? h[t - off] : 0;
        __syncthreads();
        if (t < 128) h[t] += v;
        __syncthreads();
    }
    int bs = bstart[b];
    if (t < 128) {
        int ex = t ? h[t - 1] : 0;
        cur[t] = ex;
        int r = (b << 7) + t;
        if (r < N_NODES) rowptr[r] = bs + ex;
    }
    __syncthreads();
    // scatter to final CSR positions (from LDS; overflow re-reads global)
    for (int j = t; j < T; j += 256) {
        int2 v;
        if (j < CAPE) v = ebuf[j];
        else {
            int lo = 0, hi = NBA - 1;
            while (lo < hi) {
                int mid = (lo + hi + 1) >> 1;
                if (sstart[mid] <= j) lo = mid; else hi = mid - 1;
            }
            v = tmp[goff[lo] + (j - sstart[lo])];
        }
        int p = atomicAdd(&cur[v.x >> 17], 1);
        int2 w;
        w.x = v.x & 0x1ffff;
        w.y = v.y;
        ep[bs + p] = w;
    }
}

// ---------------- converts ----------------

// transpose-convert all three weight matrices: Wt[n][k] = bf16(W[k][n])
__global__ void wcvt_k(const float* __restrict__ W1, const float* __restrict__ W2,
                       const float* __restrict__ W3, ushort* __restrict__ Wt1,
                       ushort* __restrict__ Wt2, ushort* __restrict__ Wt3) {
    int i = blockIdx.x * 256 + threadIdx.x;
    if (i < 16384) {
        int n = i >> 7, k = i & 127;
        Wt1[i] = f2bf(W1[k * 128 + n]);
        Wt2[i] = f2bf(W2[k * 128 + n]);
    }
    if (i < 8192) {
        int n = i >> 7, k = i & 127;
        Wt3[i] = f2bf(W3[k * 64 + n]);
    }
}

// ---------------- GEMM: Y[r, 0..DN) = bf16( X[r,:] @ Wt^T + bias ) ----------------
// MFMA 16x16x32 bf16. A: lane l elem j -> A[l&15][8*(l>>4)+j] (row-major X [M][128])
// B: lane l elem j -> B[8*(l>>4)+j][l&15]  (Wt stored [N][K] row-major)
// D: lane l reg i  -> D[4*(l>>4)+i][l&15]
// AF32: A is fp32 and converted in-register (fuses the cvtx pass into layer 1).

template <int DN, bool AF32>
__global__ void __launch_bounds__(256) gemm_k(const void* __restrict__ Xa,
                                              const ushort* __restrict__ Wt,
                                              const float* __restrict__ bias,
                                              ushort* __restrict__ Y) {
    constexpr int NT = DN / 16;
    const ushort* Xb = (const ushort*)Xa;
    const float* Xf = (const float*)Xa;
    int wv = threadIdx.x >> 6;
    int l = threadIdx.x & 63;
    int lg = l >> 4, lm = l & 15;
    int rbase = blockIdx.x * 64 + wv * 16;

    int arow = rbase + lm;
    if (arow > N_NODES - 1) arow = N_NODES - 1;     // clamp (stores predicated)

    f32x4 acc[NT];
#pragma unroll
    for (int n = 0; n < NT; n++) acc[n] = (f32x4){0.f, 0.f, 0.f, 0.f};

#pragma unroll
    for (int kk = 0; kk < 4; ++kk) {
        short8 a;
        if constexpr (AF32) {
            const float* ap = Xf + (size_t)arow * 128 + kk * 32 + lg * 8;
            float4 u = *(const float4*)ap;
            float4 v = *(const float4*)(ap + 4);
            a = (short8){(short)f2bf(u.x), (short)f2bf(u.y), (short)f2bf(u.z), (short)f2bf(u.w),
                         (short)f2bf(v.x), (short)f2bf(v.y), (short)f2bf(v.z), (short)f2bf(v.w)};
        } else {
            a = *(const short8*)(Xb + (size_t)arow * 128 + kk * 32 + lg * 8);
        }
#pragma unroll
        for (int n = 0; n < NT; ++n) {
            short8 b = *(const short8*)(Wt + (size_t)(n * 16 + lm) * 128 + kk * 32 + lg * 8);
            acc[n] = __builtin_amdgcn_mfma_f32_16x16x32_bf16(a, b, acc[n], 0, 0, 0);
        }
    }

    int r0 = rbase + lg * 4;
#pragma unroll
    for (int n = 0; n < NT; ++n) {
        int c = n * 16 + lm;
        float bj = bias[c];
#pragma unroll
        for (int i = 0; i < 4; ++i) {
            int r = r0 + i;
            if (r < N_NODES) Y[(size_t)r * DN + c] = f2bf(acc[n][i] + bj);
        }
    }
}

// ---------------- SpMM (CSR, one wave per row; 32 lanes per edge, 2 edges/wave) ------
// D=128: lane handles dims [hl*4, hl*4+4) as uint2 (4 bf16); halves take even/odd
// edges; one shfl_xor(32) folds the partial sums; lanes 0-31 store uint2.
// D=64:  lane handles dims [hl*2, hl*2+2) as uint (2 bf16); fp32 float2 store.

template <int D, bool RELU, bool OUT_BF16>
__global__ void __launch_bounds__(256) spmm_k(const int* __restrict__ rowptr,
                                              const int2* __restrict__ ep,
                                              const ushort* __restrict__ xb,
                                              void* __restrict__ y) {
    int w = blockIdx.x * 4 + (threadIdx.x >> 6);
    int lane = threadIdx.x & 63;
    if (w >= N_NODES) return;
    int s = rowptr[w], e = rowptr[w + 1];
    int half = lane >> 5;     // 0: even edge of pair, 1: odd edge
    int hl = lane & 31;

    if (D == 128) {
        const uint2* xp = (const uint2*)xb;          // row stride 32 uint2
        float a0 = 0.f, a1 = 0.f, a2 = 0.f, a3 = 0.f;
        int i = s;
        if ((e - s) & 1) {                            // odd-degree prologue (predicated)
            int2 e0 = ep[i];
            uint2 x0 = xp[e0.x * 32 + hl];            // both halves same addr -> broadcast
            float v0 = half ? 0.f : __int_as_float(e0.y);
            a0 = fmaf(v0, bflo(x0.x), a0); a1 = fmaf(v0, bfhi(x0.x), a1);
            a2 = fmaf(v0, bflo(x0.y), a2); a3 = fmaf(v0, bfhi(x0.y), a3);
            ++i;
        }
        for (; i + 3 < e; i += 4) {                   // 4 edges per iter (2 per half)
            int2 e0 = ep[i + half];
            int2 e1 = ep[i + 2 + half];
            uint2 x0 = xp[e0.x * 32 + hl];
            uint2 x1 = xp[e1.x * 32 + hl];
            float v0 = __int_as_float(e0.y), v1 = __int_as_float(e1.y);
            a0 = fmaf(v0, bflo(x0.x), a0); a1 = fmaf(v0, bfhi(x0.x), a1);
            a2 = fmaf(v0, bflo(x0.y), a2); a3 = fmaf(v0, bfhi(x0.y), a3);
            a0 = fmaf(v1, bflo(x1.x), a0); a1 = fmaf(v1, bfhi(x1.x), a1);
            a2 = fmaf(v1, bflo(x1.y), a2); a3 = fmaf(v1, bfhi(x1.y), a3);
        }
        if (i < e) {                                  // 2 remaining
            int2 e0 = ep[i + half];
            uint2 x0 = xp[e0.x * 32 + hl];
            float v0 = __int_as_float(e0.y);
            a0 = fmaf(v0, bflo(x0.x), a0); a1 = fmaf(v0, bfhi(x0.x), a1);
            a2 = fmaf(v0, bflo(x0.y), a2); a3 = fmaf(v0, bfhi(x0.y), a3);
        }
        a0 += __shfl_xor(a0, 32);
        a1 += __shfl_xor(a1, 32);
        a2 += __shfl_xor(a2, 32);
        a3 += __shfl_xor(a3, 32);
        if (RELU) {
            a0 = fmaxf(a0, 0.f); a1 = fmaxf(a1, 0.f);
            a2 = fmaxf(a2, 0.f); a3 = fmaxf(a3, 0.f);
        }
        if (half == 0) {
            uint2 o;
            o.x = (uint)f2bf(a0) | ((uint)f2bf(a1) << 16);
            o.y = (uint)f2bf(a2) | ((uint)f2bf(a3) << 16);
            ((uint2*)y)[w * 32 + hl] = o;
        }
    } else {  // D == 64
        const uint* xp = (const uint*)xb;             // row stride 32 uints
        float a0 = 0.f, a1 = 0.f;
        int i = s;
        if ((e - s) & 1) {
            int2 e0 = ep[i];
            uint x0 = xp[e0.x * 32 + hl];
            float v0 = half ? 0.f : __int_as_float(e0.y);
            a0 = fmaf(v0, bflo(x0), a0); a1 = fmaf(v0, bfhi(x0), a1);
            ++i;
        }
        for (; i + 3 < e; i += 4) {
            int2 e0 = ep[i + half];
            int2 e1 = ep[i + 2 + half];
            uint x0 = xp[e0.x * 32 + hl];
            uint x1 = xp[e1.x * 32 + hl];
            float v0 = __int_as_float(e0.y), v1 = __int_as_float(e1.y);
            a0 = fmaf(v0, bflo(x0), a0); a1 = fmaf(v0, bfhi(x0), a1);
            a0 = fmaf(v1, bflo(x1), a0); a1 = fmaf(v1, bfhi(x1), a1);
        }
        if (i < e) {
            int2 e0 = ep[i + half];
            uint x0 = xp[e0.x * 32 + hl];
            float v0 = __int_as_float(e0.y);
            a0 = fmaf(v0, bflo(x0), a0); a1 = fmaf(v0, bfhi(x0), a1);
        }
        a0 += __shfl_xor(a0, 32);
        a1 += __shfl_xor(a1, 32);
        if (RELU) { a0 = fmaxf(a0, 0.f); a1 = fmaxf(a1, 0.f); }
        if (half == 0) {
            float2 o; o.x = a0; o.y = a1;
            ((float2*)y)[w * 32 + hl] = o;            // final output fp32
        }
    }
}

// ---------------- launch ----------------

extern "C" void kernel_launch(void* const* d_in, const int* in_sizes, int n_in,
                              void* d_out, int out_size, void* d_ws, size_t ws_size,
                              hipStream_t stream) {
    const float* x    = (const float*)d_in[0];
    const float* vals = (const float*)d_in[1];
    const float* W1   = (const float*)d_in[2];
    const float* b1   = (const float*)d_in[3];
    const float* W2   = (const float*)d_in[4];
    const float* b2   = (const float*)d_in[5];
    const float* W3   = (const float*)d_in[6];
    const float* b3   = (const float*)d_in[7];
    const int* row    = (const int*)d_in[8];
    const int* col    = (const int*)d_in[9];
    float* out = (float*)d_out;

    char* ws = (char*)d_ws;
    int2*   ep     = (int2*)  (ws + 0);          // 12,800,000
    int*    rowptr = (int*)   (ws + 12800000);   // 400,004
    ushort* Wt1    = (ushort*)(ws + 13601024);   // 32,768
    ushort* Wt2    = (ushort*)(ws + 13633792);   // 32,768
    ushort* Wt3    = (ushort*)(ws + 13666560);   // 16,384
    ushort* g64    = (ushort*)(ws + 16000000);   // 12,800,000 (layer-3 gemm out)
    ushort* g      = (ushort*)(ws + 41600000);   // 25,600,000
    ushort* sbuf   = (ushort*)(ws + 67200000);   // 25,600,000  (total 92.8MB)

    // build-time aliases: tmp lives in g (dead until gemm L1); tables live in sbuf
    // (dead until spmm L1 writes it). All build kernels complete before then.
    int2* tmp    = (int2*)g;                     // NBA*EPB*8 = 12,845,056 <= 25.6MB
    int*  gcount = (int*)sbuf;                   // 3,128
    int*  bstart = (int*)(ws + 67200000 + 4096); // 3,128
    int*  offT   = (int*)(ws + 67200000 + 8192); // (NBK+1)*NBA*4 = 613,872

    // CSR build (counting sort by 128-row bucket)
    hipMemsetAsync(gcount, 0, NBK * sizeof(int), stream);
    hipLaunchKernelGGL(binA_k, dim3(NBA), dim3(1024), 0, stream,
                       row, col, vals, tmp, gcount, offT);
    hipLaunchKernelGGL(bscan_k, dim3(1), dim3(1024), 0, stream, gcount, bstart, rowptr);
    hipLaunchKernelGGL(binB_k, dim3(NBK), dim3(256), 0, stream,
                       tmp, offT, bstart, rowptr, ep);

    // weight converts
    hipLaunchKernelGGL(wcvt_k, dim3(64), dim3(256), 0, stream, W1, W2, W3, Wt1, Wt2, Wt3);

    const int GEMM_GRID = (N_NODES + 63) / 64;   // 1563
    const int SPMM_GRID = (N_NODES + 3) / 4;     // 25000

    // layer 1 (gemm reads fp32 x directly, converts in-register)
    hipLaunchKernelGGL((gemm_k<128, true>), dim3(GEMM_GRID), dim3(256), 0, stream, x, Wt1, b1, g);
    hipLaunchKernelGGL((spmm_k<128, true, true>), dim3(SPMM_GRID), dim3(256), 0, stream,
                       rowptr, ep, g, sbuf);
    // layer 2
    hipLaunchKernelGGL((gemm_k<128, false>), dim3(GEMM_GRID), dim3(256), 0, stream, sbuf, Wt2, b2, g);
    hipLaunchKernelGGL((spmm_k<128, true, true>), dim3(SPMM_GRID), dim3(256), 0, stream,
                       rowptr, ep, g, sbuf);
    // layer 3
    hipLaunchKernelGGL((gemm_k<64, false>), dim3(GEMM_GRID), dim3(256), 0, stream, sbuf, Wt3, b3, g64);
    hipLaunchKernelGGL((spmm_k<64, false, false>), dim3(SPMM_GRID), dim3(256), 0, stream,
                       rowptr, ep, g64, out);
}

// Round 4
// 314.062 us; speedup vs baseline: 1.9109x; 1.1102x over previous
//
#include <hip/hip_runtime.h>

#define N_NODES 100000
#define N_EDGES 1600000

#define NBK 782    // row buckets of 128 rows: ceil(100000/128)
#define EPB 8192   // edges per binA block
#define NBA 196    // binA blocks: 196*8192 = 1,605,632 >= N_EDGES
#define CAPE 4096  // LDS edge-stage capacity in binB (mean bucket = 2046)

typedef __attribute__((ext_vector_type(8))) short short8;
typedef __attribute__((ext_vector_type(4))) float f32x4;

__device__ __forceinline__ ushort f2bf(float f) {
    uint u = __float_as_uint(f);
    return (ushort)((u + 0x7fff + ((u >> 16) & 1)) >> 16);   // RNE
}
__device__ __forceinline__ float bflo(uint p) { return __uint_as_float(p << 16); }
__device__ __forceinline__ float bfhi(uint p) { return __uint_as_float(p & 0xffff0000u); }

// ---------------- CSR build: two-pass counting sort by 128-row bucket ----------------

__global__ void __launch_bounds__(1024) binA_k(const int* __restrict__ row,
                                               const int* __restrict__ col,
                                               const float* __restrict__ vals,
                                               int2* __restrict__ tmp,
                                               int* __restrict__ gcount,
                                               int* __restrict__ offT) {
    __shared__ int h[NBK];
    __shared__ int cur[NBK];
    __shared__ int sh[1024];
    int t = threadIdx.x;
    int base = blockIdx.x * EPB;

    // stage 8 edges/thread in registers (row/col/vals each read exactly once)
    int rr[8], cc[8];
    float vv[8];
#pragma unroll
    for (int u = 0; u < 8; ++u) {
        int e = base + u * 1024 + t;
        bool ok = (e < N_EDGES);
        rr[u] = ok ? row[e] : -1;
        cc[u] = ok ? col[e] : 0;
        vv[u] = ok ? vals[e] : 0.f;
    }

    if (t < NBK) h[t] = 0;
    __syncthreads();
#pragma unroll
    for (int u = 0; u < 8; ++u)
        if (rr[u] >= 0) atomicAdd(&h[rr[u] >> 7], 1);
    __syncthreads();
    if (t < NBK && h[t]) atomicAdd(&gcount[t], h[t]);
    // exclusive scan of h over NBK (padded to 1024)
    sh[t] = (t < NBK) ? h[t] : 0;
    __syncthreads();
    for (int off = 1; off < 1024; off <<= 1) {
        int v = (t >= off) ? sh[t - off] : 0;
        __syncthreads();
        sh[t] += v;
        __syncthreads();
    }
    if (t < NBK) {
        int ex = t ? sh[t - 1] : 0;
        cur[t] = ex;
        offT[t * NBA + blockIdx.x] = ex;
    }
    if (t == NBK - 1) offT[NBK * NBA + blockIdx.x] = sh[t];  // row NBK = edges in block
    __syncthreads();
    // scatter into block-private region, grouped by bucket
#pragma unroll
    for (int u = 0; u < 8; ++u) {
        if (rr[u] >= 0) {
            int p = atomicAdd(&cur[rr[u] >> 7], 1);
            int2 v;
            v.x = ((rr[u] & 127) << 17) | cc[u];   // 7-bit row-in-bucket | 17-bit col
            v.y = __float_as_int(vv[u]);
            tmp[base + p] = v;
        }
    }
}

// exclusive scan of the 782 bucket totals -> bstart; also rowptr[N] = E
__global__ void __launch_bounds__(1024) bscan_k(const int* __restrict__ gcount,
                                                int* __restrict__ bstart,
                                                int* __restrict__ rowptr) {
    __shared__ int sh[1024];
    int t = threadIdx.x;
    sh[t] = (t < NBK) ? gcount[t] : 0;
    __syncthreads();
    for (int off = 1; off < 1024; off <<= 1) {
        int v = (t >= off) ? sh[t - off] : 0;
        __syncthreads();
        sh[t] += v;
        __syncthreads();
    }
    if (t < NBK) bstart[t] = t ? sh[t - 1] : 0;
    if (t == 0) rowptr[N_NODES] = N_EDGES;
}

// Phase B: one block per bucket; flat-index gather, LDS stage, scatter from LDS.

__global__ void __launch_bounds__(256) binB_k(const int2* __restrict__ tmp,
                                              const int* __restrict__ offT,
                                              const int* __restrict__ bstart,
                                              int* __restrict__ rowptr,
                                              int2* __restrict__ ep) {
    __shared__ int goff[NBA];
    __shared__ int sstart[NBA];
    __shared__ int s_scan[256];
    __shared__ int h[128];
    __shared__ int cur[128];
    __shared__ int2 ebuf[CAPE];
    __shared__ int sT;
    int b = blockIdx.x, t = threadIdx.x;

    int c = 0;
    if (t < NBA) {
        int o0 = offT[b * NBA + t];
        int o1 = offT[(b + 1) * NBA + t];
        c = o1 - o0;
        goff[t] = t * EPB + o0;
    }
    s_scan[t] = c;
    __syncthreads();
    for (int off = 1; off < 256; off <<= 1) {
        int v = (t >= off) ? s_scan[t - off] : 0;
        __syncthreads();
        s_scan[t] += v;
        __syncthreads();
    }
    if (t < NBA) sstart[t] = s_scan[t] - c;
    if (t == NBA - 1) sT = s_scan[t];
    if (t < 128) h[t] = 0;
    __syncthreads();
    int T = sT;

    // load + histogram + stage
    for (int j = t; j < T; j += 256) {
        int lo = 0, hi = NBA - 1;            // last s with sstart[s] <= j
        while (lo < hi) {
            int mid = (lo + hi + 1) >> 1;
            if (sstart[mid] <= j) lo = mid; else hi = mid - 1;
        }
        int2 v = tmp[goff[lo] + (j - sstart[lo])];
        atomicAdd(&h[v.x >> 17], 1);
        if (j < CAPE) ebuf[j] = v;
    }
    __syncthreads();
    // exclusive scan over 128 bins
    for (int off = 1; off < 128; off <<= 1) {
        int v = (t >= off && t < 128) ? h[t - off] : 0;
        __syncthreads();
        if (t < 128) h[t] += v;
        __syncthreads();
    }
    int bs = bstart[b];
    if (t < 128) {
        int ex = t ? h[t - 1] : 0;
        cur[t] = ex;
        int r = (b << 7) + t;
        if (r < N_NODES) rowptr[r] = bs + ex;
    }
    __syncthreads();
    // scatter to final CSR positions (from LDS; overflow re-reads global)
    for (int j = t; j < T; j += 256) {
        int2 v;
        if (j < CAPE) v = ebuf[j];
        else {
            int lo = 0, hi = NBA - 1;
            while (lo < hi) {
                int mid = (lo + hi + 1) >> 1;
                if (sstart[mid] <= j) lo = mid; else hi = mid - 1;
            }
            v = tmp[goff[lo] + (j - sstart[lo])];
        }
        int p = atomicAdd(&cur[v.x >> 17], 1);
        int2 w;
        w.x = v.x & 0x1ffff;
        w.y = v.y;
        ep[bs + p] = w;
    }
}

// ---------------- converts ----------------

// transpose-convert all three weight matrices: Wt[n][k] = bf16(W[k][n])
__global__ void wcvt_k(const float* __restrict__ W1, const float* __restrict__ W2,
                       const float* __restrict__ W3, ushort* __restrict__ Wt1,
                       ushort* __restrict__ Wt2, ushort* __restrict__ Wt3) {
    int i = blockIdx.x * 256 + threadIdx.x;
    if (i < 16384) {
        int n = i >> 7, k = i & 127;
        Wt1[i] = f2bf(W1[k * 128 + n]);
        Wt2[i] = f2bf(W2[k * 128 + n]);
    }
    if (i < 8192) {
        int n = i >> 7, k = i & 127;
        Wt3[i] = f2bf(W3[k * 64 + n]);
    }
}

// ---------------- GEMM: Y[r, 0..DN) = bf16( X[r,:] @ Wt^T + bias ) ----------------
// MFMA 16x16x32 bf16. A: lane l elem j -> A[l&15][8*(l>>4)+j] (row-major X [M][128])
// B: lane l elem j -> B[8*(l>>4)+j][l&15]  (Wt stored [N][K] row-major)
// D: lane l reg i  -> D[4*(l>>4)+i][l&15]
// AF32: A is fp32 and converted in-register (fuses the cvtx pass into layer 1).

template <int DN, bool AF32>
__global__ void __launch_bounds__(256) gemm_k(const void* __restrict__ Xa,
                                              const ushort* __restrict__ Wt,
                                              const float* __restrict__ bias,
                                              ushort* __restrict__ Y) {
    constexpr int NT = DN / 16;
    const ushort* Xb = (const ushort*)Xa;
    const float* Xf = (const float*)Xa;
    int wv = threadIdx.x >> 6;
    int l = threadIdx.x & 63;
    int lg = l >> 4, lm = l & 15;
    int rbase = blockIdx.x * 64 + wv * 16;

    int arow = rbase + lm;
    if (arow > N_NODES - 1) arow = N_NODES - 1;     // clamp (stores predicated)

    f32x4 acc[NT];
#pragma unroll
    for (int n = 0; n < NT; n++) acc[n] = (f32x4){0.f, 0.f, 0.f, 0.f};

#pragma unroll
    for (int kk = 0; kk < 4; ++kk) {
        short8 a;
        if constexpr (AF32) {
            const float* ap = Xf + (size_t)arow * 128 + kk * 32 + lg * 8;
            float4 u = *(const float4*)ap;
            float4 v = *(const float4*)(ap + 4);
            a = (short8){(short)f2bf(u.x), (short)f2bf(u.y), (short)f2bf(u.z), (short)f2bf(u.w),
                         (short)f2bf(v.x), (short)f2bf(v.y), (short)f2bf(v.z), (short)f2bf(v.w)};
        } else {
            a = *(const short8*)(Xb + (size_t)arow * 128 + kk * 32 + lg * 8);
        }
#pragma unroll
        for (int n = 0; n < NT; ++n) {
            short8 b = *(const short8*)(Wt + (size_t)(n * 16 + lm) * 128 + kk * 32 + lg * 8);
            acc[n] = __builtin_amdgcn_mfma_f32_16x16x32_bf16(a, b, acc[n], 0, 0, 0);
        }
    }

    int r0 = rbase + lg * 4;
#pragma unroll
    for (int n = 0; n < NT; ++n) {
        int c = n * 16 + lm;
        float bj = bias[c];
#pragma unroll
        for (int i = 0; i < 4; ++i) {
            int r = r0 + i;
            if (r < N_NODES) Y[(size_t)r * DN + c] = f2bf(acc[n][i] + bj);
        }
    }
}

// ---------------- SpMM (CSR, one wave per row; 16 lanes/edge, 4 edges/instr) ---------
// D=128: lane handles dims [hl*8, hl*8+8) as uint4 (8 bf16); lane groups of 16 take
// edges i+0..i+3; unroll x2 puts 8 edges (16 lines) in flight. Butterfly fold
// (shfl_xor 16,32); lanes 0-15 store uint4 (256B per row, coalesced).
// D=64:  lane handles dims [hl*4, hl*4+4) as uint2 (4 bf16); float4 store (fp32 out).

template <int D, bool RELU>
__global__ void __launch_bounds__(256) spmm_k(const int* __restrict__ rowptr,
                                              const int2* __restrict__ ep,
                                              const ushort* __restrict__ xb,
                                              void* __restrict__ y) {
    int w = blockIdx.x * 4 + (threadIdx.x >> 6);
    int lane = threadIdx.x & 63;
    if (w >= N_NODES) return;
    int s = rowptr[w], e = rowptr[w + 1];
    int eidx = lane >> 4;     // which of 4 edges this lane group handles
    int hl = lane & 15;       // dim-chunk within the edge

    if (D == 128) {
        const uint4* xp = (const uint4*)xb;          // row stride 16 uint4
        float a0 = 0.f, a1 = 0.f, a2 = 0.f, a3 = 0.f;
        float a4 = 0.f, a5 = 0.f, a6 = 0.f, a7 = 0.f;
        int i = s;
        int rem = (e - s) & 3;
        if (rem) {                                    // masked 4-edge pass
            int j = i + (eidx < rem ? eidx : rem - 1);
            int2 e0 = ep[j];
            uint4 x0 = xp[e0.x * 16 + hl];
            float v0 = (eidx < rem) ? __int_as_float(e0.y) : 0.f;
            a0 = fmaf(v0, bflo(x0.x), a0); a1 = fmaf(v0, bfhi(x0.x), a1);
            a2 = fmaf(v0, bflo(x0.y), a2); a3 = fmaf(v0, bfhi(x0.y), a3);
            a4 = fmaf(v0, bflo(x0.z), a4); a5 = fmaf(v0, bfhi(x0.z), a5);
            a6 = fmaf(v0, bflo(x0.w), a6); a7 = fmaf(v0, bfhi(x0.w), a7);
            i += rem;
        }
        if ((e - i) & 4) {                            // single 4-edge pass
            int2 e0 = ep[i + eidx];
            uint4 x0 = xp[e0.x * 16 + hl];
            float v0 = __int_as_float(e0.y);
            a0 = fmaf(v0, bflo(x0.x), a0); a1 = fmaf(v0, bfhi(x0.x), a1);
            a2 = fmaf(v0, bflo(x0.y), a2); a3 = fmaf(v0, bfhi(x0.y), a3);
            a4 = fmaf(v0, bflo(x0.z), a4); a5 = fmaf(v0, bfhi(x0.z), a5);
            a6 = fmaf(v0, bflo(x0.w), a6); a7 = fmaf(v0, bfhi(x0.w), a7);
            i += 4;
        }
        for (; i < e; i += 8) {                       // 8 edges in flight
            int2 e0 = ep[i + eidx];
            int2 e1 = ep[i + 4 + eidx];
            uint4 x0 = xp[e0.x * 16 + hl];
            uint4 x1 = xp[e1.x * 16 + hl];
            float v0 = __int_as_float(e0.y), v1 = __int_as_float(e1.y);
            a0 = fmaf(v0, bflo(x0.x), a0); a1 = fmaf(v0, bfhi(x0.x), a1);
            a2 = fmaf(v0, bflo(x0.y), a2); a3 = fmaf(v0, bfhi(x0.y), a3);
            a4 = fmaf(v0, bflo(x0.z), a4); a5 = fmaf(v0, bfhi(x0.z), a5);
            a6 = fmaf(v0, bflo(x0.w), a6); a7 = fmaf(v0, bfhi(x0.w), a7);
            a0 = fmaf(v1, bflo(x1.x), a0); a1 = fmaf(v1, bfhi(x1.x), a1);
            a2 = fmaf(v1, bflo(x1.y), a2); a3 = fmaf(v1, bfhi(x1.y), a3);
            a4 = fmaf(v1, bflo(x1.z), a4); a5 = fmaf(v1, bfhi(x1.z), a5);
            a6 = fmaf(v1, bflo(x1.w), a6); a7 = fmaf(v1, bfhi(x1.w), a7);
        }
        a0 += __shfl_xor(a0, 16); a0 += __shfl_xor(a0, 32);
        a1 += __shfl_xor(a1, 16); a1 += __shfl_xor(a1, 32);
        a2 += __shfl_xor(a2, 16); a2 += __shfl_xor(a2, 32);
        a3 += __shfl_xor(a3, 16); a3 += __shfl_xor(a3, 32);
        a4 += __shfl_xor(a4, 16); a4 += __shfl_xor(a4, 32);
        a5 += __shfl_xor(a5, 16); a5 += __shfl_xor(a5, 32);
        a6 += __shfl_xor(a6, 16); a6 += __shfl_xor(a6, 32);
        a7 += __shfl_xor(a7, 16); a7 += __shfl_xor(a7, 32);
        if (RELU) {
            a0 = fmaxf(a0, 0.f); a1 = fmaxf(a1, 0.f); a2 = fmaxf(a2, 0.f); a3 = fmaxf(a3, 0.f);
            a4 = fmaxf(a4, 0.f); a5 = fmaxf(a5, 0.f); a6 = fmaxf(a6, 0.f); a7 = fmaxf(a7, 0.f);
        }
        if (eidx == 0) {
            uint4 o;
            o.x = (uint)f2bf(a0) | ((uint)f2bf(a1) << 16);
            o.y = (uint)f2bf(a2) | ((uint)f2bf(a3) << 16);
            o.z = (uint)f2bf(a4) | ((uint)f2bf(a5) << 16);
            o.w = (uint)f2bf(a6) | ((uint)f2bf(a7) << 16);
            ((uint4*)y)[w * 16 + hl] = o;
        }
    } else {  // D == 64
        const uint2* xp = (const uint2*)xb;          // row stride 16 uint2
        float a0 = 0.f, a1 = 0.f, a2 = 0.f, a3 = 0.f;
        int i = s;
        int rem = (e - s) & 3;
        if (rem) {
            int j = i + (eidx < rem ? eidx : rem - 1);
            int2 e0 = ep[j];
            uint2 x0 = xp[e0.x * 16 + hl];
            float v0 = (eidx < rem) ? __int_as_float(e0.y) : 0.f;
            a0 = fmaf(v0, bflo(x0.x), a0); a1 = fmaf(v0, bfhi(x0.x), a1);
            a2 = fmaf(v0, bflo(x0.y), a2); a3 = fmaf(v0, bfhi(x0.y), a3);
            i += rem;
        }
        if ((e - i) & 4) {
            int2 e0 = ep[i + eidx];
            uint2 x0 = xp[e0.x * 16 + hl];
            float v0 = __int_as_float(e0.y);
            a0 = fmaf(v0, bflo(x0.x), a0); a1 = fmaf(v0, bfhi(x0.x), a1);
            a2 = fmaf(v0, bflo(x0.y), a2); a3 = fmaf(v0, bfhi(x0.y), a3);
            i += 4;
        }
        for (; i < e; i += 8) {
            int2 e0 = ep[i + eidx];
            int2 e1 = ep[i + 4 + eidx];
            uint2 x0 = xp[e0.x * 16 + hl];
            uint2 x1 = xp[e1.x * 16 + hl];
            float v0 = __int_as_float(e0.y), v1 = __int_as_float(e1.y);
            a0 = fmaf(v0, bflo(x0.x), a0); a1 = fmaf(v0, bfhi(x0.x), a1);
            a2 = fmaf(v0, bflo(x0.y), a2); a3 = fmaf(v0, bfhi(x0.y), a3);
            a0 = fmaf(v1, bflo(x1.x), a0); a1 = fmaf(v1, bfhi(x1.x), a1);
            a2 = fmaf(v1, bflo(x1.y), a2); a3 = fmaf(v1, bfhi(x1.y), a3);
        }
        a0 += __shfl_xor(a0, 16); a0 += __shfl_xor(a0, 32);
        a1 += __shfl_xor(a1, 16); a1 += __shfl_xor(a1, 32);
        a2 += __shfl_xor(a2, 16); a2 += __shfl_xor(a2, 32);
        a3 += __shfl_xor(a3, 16); a3 += __shfl_xor(a3, 32);
        if (RELU) {
            a0 = fmaxf(a0, 0.f); a1 = fmaxf(a1, 0.f);
            a2 = fmaxf(a2, 0.f); a3 = fmaxf(a3, 0.f);
        }
        if (eidx == 0) {
            float4 o; o.x = a0; o.y = a1; o.z = a2; o.w = a3;
            ((float4*)y)[w * 16 + hl] = o;            // final output fp32
        }
    }
}

// ---------------- launch ----------------

extern "C" void kernel_launch(void* const* d_in, const int* in_sizes, int n_in,
                              void* d_out, int out_size, void* d_ws, size_t ws_size,
                              hipStream_t stream) {
    const float* x    = (const float*)d_in[0];
    const float* vals = (const float*)d_in[1];
    const float* W1   = (const float*)d_in[2];
    const float* b1   = (const float*)d_in[3];
    const float* W2   = (const float*)d_in[4];
    const float* b2   = (const float*)d_in[5];
    const float* W3   = (const float*)d_in[6];
    const float* b3   = (const float*)d_in[7];
    const int* row    = (const int*)d_in[8];
    const int* col    = (const int*)d_in[9];
    float* out = (float*)d_out;

    char* ws = (char*)d_ws;
    int2*   ep     = (int2*)  (ws + 0);          // 12,800,000
    int*    rowptr = (int*)   (ws + 12800000);   // 400,004
    ushort* Wt1    = (ushort*)(ws + 13601024);   // 32,768
    ushort* Wt2    = (ushort*)(ws + 13633792);   // 32,768
    ushort* Wt3    = (ushort*)(ws + 13666560);   // 16,384
    ushort* g64    = (ushort*)(ws + 16000000);   // 12,800,000 (layer-3 gemm out)
    ushort* g      = (ushort*)(ws + 41600000);   // 25,600,000
    ushort* sbuf   = (ushort*)(ws + 67200000);   // 25,600,000  (total 92.8MB)

    // build-time aliases: tmp lives in g (dead until gemm L1); tables live in sbuf
    // (dead until spmm L1 writes it). All build kernels complete before then.
    int2* tmp    = (int2*)g;                     // NBA*EPB*8 = 12,845,056 <= 25.6MB
    int*  gcount = (int*)sbuf;                   // 3,128
    int*  bstart = (int*)(ws + 67200000 + 4096); // 3,128
    int*  offT   = (int*)(ws + 67200000 + 8192); // (NBK+1)*NBA*4 = 613,872

    // CSR build (counting sort by 128-row bucket)
    hipMemsetAsync(gcount, 0, NBK * sizeof(int), stream);
    hipLaunchKernelGGL(binA_k, dim3(NBA), dim3(1024), 0, stream,
                       row, col, vals, tmp, gcount, offT);
    hipLaunchKernelGGL(bscan_k, dim3(1), dim3(1024), 0, stream, gcount, bstart, rowptr);
    hipLaunchKernelGGL(binB_k, dim3(NBK), dim3(256), 0, stream,
                       tmp, offT, bstart, rowptr, ep);

    // weight converts
    hipLaunchKernelGGL(wcvt_k, dim3(64), dim3(256), 0, stream, W1, W2, W3, Wt1, Wt2, Wt3);

    const int GEMM_GRID = (N_NODES + 63) / 64;   // 1563
    const int SPMM_GRID = (N_NODES + 3) / 4;     // 25000

    // layer 1 (gemm reads fp32 x directly, converts in-register)
    hipLaunchKernelGGL((gemm_k<128, true>), dim3(GEMM_GRID), dim3(256), 0, stream, x, Wt1, b1, g);
    hipLaunchKernelGGL((spmm_k<128, true>), dim3(SPMM_GRID), dim3(256), 0, stream,
                       rowptr, ep, g, sbuf);
    // layer 2
    hipLaunchKernelGGL((gemm_k<128, false>), dim3(GEMM_GRID), dim3(256), 0, stream, sbuf, Wt2, b2, g);
    hipLaunchKernelGGL((spmm_k<128, true>), dim3(SPMM_GRID), dim3(256), 0, stream,
                       rowptr, ep, g, sbuf);
    // layer 3
    hipLaunchKernelGGL((gemm_k<64, false>), dim3(GEMM_GRID), dim3(256), 0, stream, sbuf, Wt3, b3, g64);
    hipLaunchKernelGGL((spmm_k<64, false>), dim3(SPMM_GRID), dim3(256), 0, stream,
                       rowptr, ep, g64, out);
}

// Round 5
// 304.876 us; speedup vs baseline: 1.9684x; 1.0301x over previous
//
#include <hip/hip_runtime.h>

#define N_NODES 100000
#define N_EDGES 1600000

#define NBK 782    // row buckets of 128 rows: ceil(100000/128)
#define EPB 8192   // edges per binA block
#define NBA 196    // binA blocks: 196*8192 = 1,605,632 >= N_EDGES
#define CAPE 4096  // LDS edge-stage capacity in binB (mean bucket = 2046)

typedef __attribute__((ext_vector_type(8))) short short8;
typedef __attribute__((ext_vector_type(4))) float f32x4;

__device__ __forceinline__ ushort f2bf(float f) {
    uint u = __float_as_uint(f);
    return (ushort)((u + 0x7fff + ((u >> 16) & 1)) >> 16);   // RNE
}
__device__ __forceinline__ float bflo(uint p) { return __uint_as_float(p << 16); }
__device__ __forceinline__ float bfhi(uint p) { return __uint_as_float(p & 0xffff0000u); }

// ---------------- CSR build: two-pass counting sort by 128-row bucket ----------------

__global__ void __launch_bounds__(1024) binA_k(const int* __restrict__ row,
                                               const int* __restrict__ col,
                                               const float* __restrict__ vals,
                                               int2* __restrict__ tmp,
                                               int* __restrict__ gcount,
                                               int* __restrict__ offT) {
    __shared__ int h[NBK];
    __shared__ int cur[NBK];
    __shared__ int sh[1024];
    int t = threadIdx.x;
    int base = blockIdx.x * EPB;

    // stage 8 edges/thread in registers (row/col/vals each read exactly once)
    int rr[8], cc[8];
    float vv[8];
#pragma unroll
    for (int u = 0; u < 8; ++u) {
        int e = base + u * 1024 + t;
        bool ok = (e < N_EDGES);
        rr[u] = ok ? row[e] : -1;
        cc[u] = ok ? col[e] : 0;
        vv[u] = ok ? vals[e] : 0.f;
    }

    if (t < NBK) h[t] = 0;
    __syncthreads();
#pragma unroll
    for (int u = 0; u < 8; ++u)
        if (rr[u] >= 0) atomicAdd(&h[rr[u] >> 7], 1);
    __syncthreads();
    if (t < NBK && h[t]) atomicAdd(&gcount[t], h[t]);
    // exclusive scan of h over NBK (padded to 1024)
    sh[t] = (t < NBK) ? h[t] : 0;
    __syncthreads();
    for (int off = 1; off < 1024; off <<= 1) {
        int v = (t >= off) ? sh[t - off] : 0;
        __syncthreads();
        sh[t] += v;
        __syncthreads();
    }
    if (t < NBK) {
        int ex = t ? sh[t - 1] : 0;
        cur[t] = ex;
        offT[t * NBA + blockIdx.x] = ex;
    }
    if (t == NBK - 1) offT[NBK * NBA + blockIdx.x] = sh[t];  // row NBK = edges in block
    __syncthreads();
    // scatter into block-private region, grouped by bucket
#pragma unroll
    for (int u = 0; u < 8; ++u) {
        if (rr[u] >= 0) {
            int p = atomicAdd(&cur[rr[u] >> 7], 1);
            int2 v;
            v.x = ((rr[u] & 127) << 17) | cc[u];   // 7-bit row-in-bucket | 17-bit col
            v.y = __float_as_int(vv[u]);
            tmp[base + p] = v;
        }
    }
}

// exclusive scan of the 782 bucket totals -> bstart; also rowptr[N] = E
__global__ void __launch_bounds__(1024) bscan_k(const int* __restrict__ gcount,
                                                int* __restrict__ bstart,
                                                int* __restrict__ rowptr) {
    __shared__ int sh[1024];
    int t = threadIdx.x;
    sh[t] = (t < NBK) ? gcount[t] : 0;
    __syncthreads();
    for (int off = 1; off < 1024; off <<= 1) {
        int v = (t >= off) ? sh[t - off] : 0;
        __syncthreads();
        sh[t] += v;
        __syncthreads();
    }
    if (t < NBK) bstart[t] = t ? sh[t - 1] : 0;
    if (t == 0) rowptr[N_NODES] = N_EDGES;
}

// Phase B: one block per bucket; flat-index gather, LDS stage, scatter from LDS.

__global__ void __launch_bounds__(256) binB_k(const int2* __restrict__ tmp,
                                              const int* __restrict__ offT,
                                              const int* __restrict__ bstart,
                                              int* __restrict__ rowptr,
                                              int2* __restrict__ ep) {
    __shared__ int goff[NBA];
    __shared__ int sstart[NBA];
    __shared__ int s_scan[256];
    __shared__ int h[128];
    __shared__ int cur[128];
    __shared__ int2 ebuf[CAPE];
    __shared__ int sT;
    int b = blockIdx.x, t = threadIdx.x;

    int c = 0;
    if (t < NBA) {
        int o0 = offT[b * NBA + t];
        int o1 = offT[(b + 1) * NBA + t];
        c = o1 - o0;
        goff[t] = t * EPB + o0;
    }
    s_scan[t] = c;
    __syncthreads();
    for (int off = 1; off < 256; off <<= 1) {
        int v = (t >= off) ? s_scan[t - off] : 0;
        __syncthreads();
        s_scan[t] += v;
        __syncthreads();
    }
    if (t < NBA) sstart[t] = s_scan[t] - c;
    if (t == NBA - 1) sT = s_scan[t];
    if (t < 128) h[t] = 0;
    __syncthreads();
    int T = sT;

    // load + histogram + stage
    for (int j = t; j < T; j += 256) {
        int lo = 0, hi = NBA - 1;            // last s with sstart[s] <= j
        while (lo < hi) {
            int mid = (lo + hi + 1) >> 1;
            if (sstart[mid] <= j) lo = mid; else hi = mid - 1;
        }
        int2 v = tmp[goff[lo] + (j - sstart[lo])];
        atomicAdd(&h[v.x >> 17], 1);
        if (j < CAPE) ebuf[j] = v;
    }
    __syncthreads();
    // exclusive scan over 128 bins
    for (int off = 1; off < 128; off <<= 1) {
        int v = (t >= off && t < 128) ? h[t - off] : 0;
        __syncthreads();
        if (t < 128) h[t] += v;
        __syncthreads();
    }
    int bs = bstart[b];
    if (t < 128) {
        int ex = t ? h[t - 1] : 0;
        cur[t] = ex;
        int r = (b << 7) + t;
        if (r < N_NODES) rowptr[r] = bs + ex;
    }
    __syncthreads();
    // scatter to final CSR positions (from LDS; overflow re-reads global)
    for (int j = t; j < T; j += 256) {
        int2 v;
        if (j < CAPE) v = ebuf[j];
        else {
            int lo = 0, hi = NBA - 1;
            while (lo < hi) {
                int mid = (lo + hi + 1) >> 1;
                if (sstart[mid] <= j) lo = mid; else hi = mid - 1;
            }
            v = tmp[goff[lo] + (j - sstart[lo])];
        }
        int p = atomicAdd(&cur[v.x >> 17], 1);
        int2 w;
        w.x = v.x & 0x1ffff;
        w.y = v.y;
        ep[bs + p] = w;
    }
}

// ---------------- converts ----------------

// transpose-convert all three weight matrices: Wt[n][k] = bf16(W[k][n])
__global__ void wcvt_k(const float* __restrict__ W1, const float* __restrict__ W2,
                       const float* __restrict__ W3, ushort* __restrict__ Wt1,
                       ushort* __restrict__ Wt2, ushort* __restrict__ Wt3) {
    int i = blockIdx.x * 256 + threadIdx.x;
    if (i < 16384) {
        int n = i >> 7, k = i & 127;
        Wt1[i] = f2bf(W1[k * 128 + n]);
        Wt2[i] = f2bf(W2[k * 128 + n]);
    }
    if (i < 8192) {
        int n = i >> 7, k = i & 127;
        Wt3[i] = f2bf(W3[k * 64 + n]);
    }
}

// ---------------- GEMM: Y[r, 0..DN) = bf16( X[r,:] @ Wt^T + bias ) ----------------
// MFMA 16x16x32 bf16. A: lane l elem j -> A[l&15][8*(l>>4)+j] (row-major X [M][128])
// B: lane l elem j -> B[8*(l>>4)+j][l&15]  (Wt stored [N][K] row-major)
// D: lane l reg i  -> D[4*(l>>4)+i][l&15]
// AF32: A is fp32 and converted in-register (fuses the cvtx pass into layer 1).

template <int DN, bool AF32>
__global__ void __launch_bounds__(256) gemm_k(const void* __restrict__ Xa,
                                              const ushort* __restrict__ Wt,
                                              const float* __restrict__ bias,
                                              ushort* __restrict__ Y) {
    constexpr int NT = DN / 16;
    const ushort* Xb = (const ushort*)Xa;
    const float* Xf = (const float*)Xa;
    int wv = threadIdx.x >> 6;
    int l = threadIdx.x & 63;
    int lg = l >> 4, lm = l & 15;
    int rbase = blockIdx.x * 64 + wv * 16;

    int arow = rbase + lm;
    if (arow > N_NODES - 1) arow = N_NODES - 1;     // clamp (stores predicated)

    f32x4 acc[NT];
#pragma unroll
    for (int n = 0; n < NT; n++) acc[n] = (f32x4){0.f, 0.f, 0.f, 0.f};

#pragma unroll
    for (int kk = 0; kk < 4; ++kk) {
        short8 a;
        if constexpr (AF32) {
            const float* ap = Xf + (size_t)arow * 128 + kk * 32 + lg * 8;
            float4 u = *(const float4*)ap;
            float4 v = *(const float4*)(ap + 4);
            a = (short8){(short)f2bf(u.x), (short)f2bf(u.y), (short)f2bf(u.z), (short)f2bf(u.w),
                         (short)f2bf(v.x), (short)f2bf(v.y), (short)f2bf(v.z), (short)f2bf(v.w)};
        } else {
            a = *(const short8*)(Xb + (size_t)arow * 128 + kk * 32 + lg * 8);
        }
#pragma unroll
        for (int n = 0; n < NT; ++n) {
            short8 b = *(const short8*)(Wt + (size_t)(n * 16 + lm) * 128 + kk * 32 + lg * 8);
            acc[n] = __builtin_amdgcn_mfma_f32_16x16x32_bf16(a, b, acc[n], 0, 0, 0);
        }
    }

    int r0 = rbase + lg * 4;
#pragma unroll
    for (int n = 0; n < NT; ++n) {
        int c = n * 16 + lm;
        float bj = bias[c];
#pragma unroll
        for (int i = 0; i < 4; ++i) {
            int r = r0 + i;
            if (r < N_NODES) Y[(size_t)r * DN + c] = f2bf(acc[n][i] + bj);
        }
    }
}

// ---------------- SpMM (CSR; one lane-GROUP per row, no cross-lane reduction) --------
// D=128: 16-lane group per row (4 rows/wave). Lane hl holds dims [hl*8, hl*8+8) as
// uint4 (8 bf16). Group walks its row's edges sequentially, 4 staged per iter ->
// 16 gathers in flight per wave. No shuffles; store uint4 (256B/row, coalesced).
// D=64:  8-lane group per row (8 rows/wave); lane holds 8 dims; fp32 2x float4 store.

template <int D, bool RELU>
__global__ void __launch_bounds__(256) spmm_k(const int* __restrict__ rowptr,
                                              const int2* __restrict__ ep,
                                              const ushort* __restrict__ xb,
                                              void* __restrict__ y) {
    constexpr int LPG = (D == 128) ? 16 : 8;   // lanes per group (one row each)
    constexpr int RPB = 256 / LPG;             // rows per block
    int t = threadIdx.x;
    int g = t / LPG;
    int hl = t % LPG;
    int w = blockIdx.x * RPB + g;
    if (w >= N_NODES) return;
    int s = rowptr[w], e = rowptr[w + 1];

    const uint4* xp = (const uint4*)xb;        // row stride LPG uint4
    float a0 = 0.f, a1 = 0.f, a2 = 0.f, a3 = 0.f;
    float a4 = 0.f, a5 = 0.f, a6 = 0.f, a7 = 0.f;

    int i = s;
    for (; i + 4 <= e; i += 4) {               // 4 edges staged -> 4 gathers in flight
        int2 e0 = ep[i], e1 = ep[i + 1], e2 = ep[i + 2], e3 = ep[i + 3];
        uint4 x0 = xp[e0.x * LPG + hl];
        uint4 x1 = xp[e1.x * LPG + hl];
        uint4 x2 = xp[e2.x * LPG + hl];
        uint4 x3 = xp[e3.x * LPG + hl];
        float v0 = __int_as_float(e0.y), v1 = __int_as_float(e1.y);
        float v2 = __int_as_float(e2.y), v3 = __int_as_float(e3.y);
        a0 = fmaf(v0, bflo(x0.x), a0); a1 = fmaf(v0, bfhi(x0.x), a1);
        a2 = fmaf(v0, bflo(x0.y), a2); a3 = fmaf(v0, bfhi(x0.y), a3);
        a4 = fmaf(v0, bflo(x0.z), a4); a5 = fmaf(v0, bfhi(x0.z), a5);
        a6 = fmaf(v0, bflo(x0.w), a6); a7 = fmaf(v0, bfhi(x0.w), a7);
        a0 = fmaf(v1, bflo(x1.x), a0); a1 = fmaf(v1, bfhi(x1.x), a1);
        a2 = fmaf(v1, bflo(x1.y), a2); a3 = fmaf(v1, bfhi(x1.y), a3);
        a4 = fmaf(v1, bflo(x1.z), a4); a5 = fmaf(v1, bfhi(x1.z), a5);
        a6 = fmaf(v1, bflo(x1.w), a6); a7 = fmaf(v1, bfhi(x1.w), a7);
        a0 = fmaf(v2, bflo(x2.x), a0); a1 = fmaf(v2, bfhi(x2.x), a1);
        a2 = fmaf(v2, bflo(x2.y), a2); a3 = fmaf(v2, bfhi(x2.y), a3);
        a4 = fmaf(v2, bflo(x2.z), a4); a5 = fmaf(v2, bfhi(x2.z), a5);
        a6 = fmaf(v2, bflo(x2.w), a6); a7 = fmaf(v2, bfhi(x2.w), a7);
        a0 = fmaf(v3, bflo(x3.x), a0); a1 = fmaf(v3, bfhi(x3.x), a1);
        a2 = fmaf(v3, bflo(x3.y), a2); a3 = fmaf(v3, bfhi(x3.y), a3);
        a4 = fmaf(v3, bflo(x3.z), a4); a5 = fmaf(v3, bfhi(x3.z), a5);
        a6 = fmaf(v3, bflo(x3.w), a6); a7 = fmaf(v3, bfhi(x3.w), a7);
    }
    for (; i < e; ++i) {                       // tail (< 4 edges)
        int2 e0 = ep[i];
        uint4 x0 = xp[e0.x * LPG + hl];
        float v0 = __int_as_float(e0.y);
        a0 = fmaf(v0, bflo(x0.x), a0); a1 = fmaf(v0, bfhi(x0.x), a1);
        a2 = fmaf(v0, bflo(x0.y), a2); a3 = fmaf(v0, bfhi(x0.y), a3);
        a4 = fmaf(v0, bflo(x0.z), a4); a5 = fmaf(v0, bfhi(x0.z), a5);
        a6 = fmaf(v0, bflo(x0.w), a6); a7 = fmaf(v0, bfhi(x0.w), a7);
    }
    if (RELU) {
        a0 = fmaxf(a0, 0.f); a1 = fmaxf(a1, 0.f); a2 = fmaxf(a2, 0.f); a3 = fmaxf(a3, 0.f);
        a4 = fmaxf(a4, 0.f); a5 = fmaxf(a5, 0.f); a6 = fmaxf(a6, 0.f); a7 = fmaxf(a7, 0.f);
    }
    if (D == 128) {                             // bf16 out
        uint4 o;
        o.x = (uint)f2bf(a0) | ((uint)f2bf(a1) << 16);
        o.y = (uint)f2bf(a2) | ((uint)f2bf(a3) << 16);
        o.z = (uint)f2bf(a4) | ((uint)f2bf(a5) << 16);
        o.w = (uint)f2bf(a6) | ((uint)f2bf(a7) << 16);
        ((uint4*)y)[w * 16 + hl] = o;
    } else {                                    // fp32 out: lane covers 8 floats
        float4 o0; o0.x = a0; o0.y = a1; o0.z = a2; o0.w = a3;
        float4 o1; o1.x = a4; o1.y = a5; o1.z = a6; o1.w = a7;
        ((float4*)y)[w * 16 + hl * 2] = o0;
        ((float4*)y)[w * 16 + hl * 2 + 1] = o1;
    }
}

// ---------------- launch ----------------

extern "C" void kernel_launch(void* const* d_in, const int* in_sizes, int n_in,
                              void* d_out, int out_size, void* d_ws, size_t ws_size,
                              hipStream_t stream) {
    const float* x    = (const float*)d_in[0];
    const float* vals = (const float*)d_in[1];
    const float* W1   = (const float*)d_in[2];
    const float* b1   = (const float*)d_in[3];
    const float* W2   = (const float*)d_in[4];
    const float* b2   = (const float*)d_in[5];
    const float* W3   = (const float*)d_in[6];
    const float* b3   = (const float*)d_in[7];
    const int* row    = (const int*)d_in[8];
    const int* col    = (const int*)d_in[9];
    float* out = (float*)d_out;

    char* ws = (char*)d_ws;
    int2*   ep     = (int2*)  (ws + 0);          // 12,800,000
    int*    rowptr = (int*)   (ws + 12800000);   // 400,004
    ushort* Wt1    = (ushort*)(ws + 13601024);   // 32,768
    ushort* Wt2    = (ushort*)(ws + 13633792);   // 32,768
    ushort* Wt3    = (ushort*)(ws + 13666560);   // 16,384
    ushort* g64    = (ushort*)(ws + 16000000);   // 12,800,000 (layer-3 gemm out)
    ushort* g      = (ushort*)(ws + 41600000);   // 25,600,000
    ushort* sbuf   = (ushort*)(ws + 67200000);   // 25,600,000  (total 92.8MB)

    // build-time aliases: tmp lives in g (dead until gemm L1); tables live in sbuf
    // (dead until spmm L1 writes it). All build kernels complete before then.
    int2* tmp    = (int2*)g;                     // NBA*EPB*8 = 12,845,056 <= 25.6MB
    int*  gcount = (int*)sbuf;                   // 3,128
    int*  bstart = (int*)(ws + 67200000 + 4096); // 3,128
    int*  offT   = (int*)(ws + 67200000 + 8192); // (NBK+1)*NBA*4 = 613,872

    // CSR build (counting sort by 128-row bucket)
    hipMemsetAsync(gcount, 0, NBK * sizeof(int), stream);
    hipLaunchKernelGGL(binA_k, dim3(NBA), dim3(1024), 0, stream,
                       row, col, vals, tmp, gcount, offT);
    hipLaunchKernelGGL(bscan_k, dim3(1), dim3(1024), 0, stream, gcount, bstart, rowptr);
    hipLaunchKernelGGL(binB_k, dim3(NBK), dim3(256), 0, stream,
                       tmp, offT, bstart, rowptr, ep);

    // weight converts
    hipLaunchKernelGGL(wcvt_k, dim3(64), dim3(256), 0, stream, W1, W2, W3, Wt1, Wt2, Wt3);

    const int GEMM_GRID = (N_NODES + 63) / 64;     // 1563
    const int SPMM_GRID_128 = (N_NODES + 15) / 16; // 6250
    const int SPMM_GRID_64  = (N_NODES + 31) / 32; // 3125

    // layer 1 (gemm reads fp32 x directly, converts in-register)
    hipLaunchKernelGGL((gemm_k<128, true>), dim3(GEMM_GRID), dim3(256), 0, stream, x, Wt1, b1, g);
    hipLaunchKernelGGL((spmm_k<128, true>), dim3(SPMM_GRID_128), dim3(256), 0, stream,
                       rowptr, ep, g, sbuf);
    // layer 2
    hipLaunchKernelGGL((gemm_k<128, false>), dim3(GEMM_GRID), dim3(256), 0, stream, sbuf, Wt2, b2, g);
    hipLaunchKernelGGL((spmm_k<128, true>), dim3(SPMM_GRID_128), dim3(256), 0, stream,
                       rowptr, ep, g, sbuf);
    // layer 3
    hipLaunchKernelGGL((gemm_k<64, false>), dim3(GEMM_GRID), dim3(256), 0, stream, sbuf, Wt3, b3, g64);
    hipLaunchKernelGGL((spmm_k<64, false>), dim3(SPMM_GRID_64), dim3(256), 0, stream,
                       rowptr, ep, g64, out);
}